// Round 11
// baseline (135.441 us; speedup 1.0000x reference)
//
#include <hip/hip_runtime.h>

typedef unsigned short u16;
typedef __attribute__((ext_vector_type(8))) short short8_t;     // 8 x f16 payload (4 VGPR)
typedef __attribute__((ext_vector_type(8))) _Float16 half8_t;   // MFMA f16 operand
typedef __attribute__((ext_vector_type(4))) float f32x4;        // 16x16 MFMA accum
typedef __attribute__((ext_vector_type(16))) float f32x16;      // 32x32 MFMA accum
typedef __attribute__((ext_vector_type(4))) int int4v;

// ---- problem dims ----
#define BB    2
#define TT    2048
#define DD    1024
#define NHEAD 16
#define DKH   64
#define HH    1024
#define MR    4096          // B*T
#define CLR_EPS 1e-6f
// log2(e)/8 folded into Q so P = 2^(q'.k) = exp(q.k/8)
#define QSCALE_CONST 0.18033688011112042f

// ---- workspace byte offsets ----
#define O_WQKVT  0ull                 // f16 [3072][1024]
#define O_WOT    6291456ull           // f16 [1024][1024]
#define O_WMEAN  8388608ull           // f32  [4][1024]
#define O_BQKV   8404992ull           // f32  [3072]
#define O_BO     8417280ull           // f32  [1024]
#define O_Z      8421376ull           // f16 [4096][1024]
#define O_QKV    16809984ull          // f16 [4096][3072]  (q|k cols; v third unused)
#define O_VT     41975808ull          // f16 [B*NH][64][2048]  (keys PERMUTED within 32-groups)
#define O_ZOUT   50364416ull          // f16 [4096][1024]
#define O_LOGITS O_QKV                // f32  [4096][1024] (reuses dead qkv region)

// ---------------- helpers ----------------
__device__ __forceinline__ u16 f2h(float f) {
  _Float16 h = (_Float16)f;           // v_cvt_f16_f32 (RNE)
  return __builtin_bit_cast(u16, h);
}
__device__ __forceinline__ float h2f(u16 x) {
  return (float)__builtin_bit_cast(_Float16, x);
}

__device__ __forceinline__ f32x4 mfma16(short8_t a, short8_t b, f32x4 c) {
  return __builtin_amdgcn_mfma_f32_16x16x32_f16(
      __builtin_bit_cast(half8_t, a), __builtin_bit_cast(half8_t, b), c, 0, 0, 0);
}
__device__ __forceinline__ f32x16 mfma32(short8_t a, short8_t b, f32x16 c) {
  return __builtin_amdgcn_mfma_f32_32x32x16_f16(
      __builtin_bit_cast(half8_t, a), __builtin_bit_cast(half8_t, b), c, 0, 0, 0);
}

typedef const __attribute__((address_space(1))) unsigned int as1_u32_t;
typedef __attribute__((address_space(3))) unsigned int as3_u32_t;

__device__ __forceinline__ void async16(const void* g, void* l) {
  __builtin_amdgcn_global_load_lds((as1_u32_t*)g, (as3_u32_t*)l, 16, 0, 0);
}

// stage 2 rows (r0, r1) of a [*, 1024] f16 matrix into an LDS tile
// (row-major 64 cols = 128B rows) with the both-sides chunk swizzle.
__device__ __forceinline__ void stage2(const u16* __restrict__ G, int base_row,
                                       int r0, int r1, int k0, int schk, u16* lds) {
  const int c0 = k0 + ((schk ^ (r0 & 7)) << 3);
  const int c1 = k0 + ((schk ^ (r1 & 7)) << 3);
  async16(G + (size_t)(base_row + r0) * 1024 + c0, lds + r0 * 64 + schk * 8);
  async16(G + (size_t)(base_row + r1) * 1024 + c1, lds + r1 * 64 + schk * 8);
}

// swizzled ds_read of one 16x16x32 A/B fragment from a [256][64] f16 tile
__device__ __forceinline__ short8_t ldfrag(const u16* buf, int row, int kh, int lane) {
  const int byte = (row * 128 + ((kh * 32 + ((lane >> 4) << 3)) << 1)) ^ ((row & 7) << 4);
  return *(const short8_t*)((const char*)buf + byte);
}

// =======================================================================
// K0a: weight row-means (mean over out-dim h for each in-dim d) + biases
// =======================================================================
__global__ __launch_bounds__(256) void wprep_mean(
    const float* __restrict__ Wq, const float* __restrict__ Wk,
    const float* __restrict__ Wv, const float* __restrict__ Wo,
    const float* __restrict__ bq, const float* __restrict__ bk,
    const float* __restrict__ bv, const float* __restrict__ bo,
    float* __restrict__ wmean, float* __restrict__ bqkv_p, float* __restrict__ bo_p) {
  __shared__ float sb[4];
  const int bid = blockIdx.x, tid = threadIdx.x;
  if (bid < 4096) {
    const int m = bid >> 10, d = bid & 1023;
    const float* Wm = (m == 0) ? Wq : (m == 1) ? Wk : (m == 2) ? Wv : Wo;
    float4 x = ((const float4*)(Wm + (size_t)d * 1024))[tid];
    float s = x.x + x.y + x.z + x.w;
    #pragma unroll
    for (int dd = 32; dd; dd >>= 1) s += __shfl_xor(s, dd);
    if ((tid & 63) == 0) sb[tid >> 6] = s;
    __syncthreads();
    if (tid == 0) wmean[bid] = (sb[0] + sb[1] + sb[2] + sb[3]) * (1.f / 1024.f);
  } else {
    const int j = bid - 4096;
    const float* bb = (j == 0) ? bq : (j == 1) ? bk : (j == 2) ? bv : bo;
    float4 x = ((const float4*)bb)[tid];
    float s = x.x + x.y + x.z + x.w;
    #pragma unroll
    for (int dd = 32; dd; dd >>= 1) s += __shfl_xor(s, dd);
    if ((tid & 63) == 0) sb[tid >> 6] = s;
    __syncthreads();
    const float mean = (sb[0] + sb[1] + sb[2] + sb[3]) * (1.f / 1024.f);
    float* dst = (j < 3) ? (bqkv_p + j * 1024) : bo_p;
    float4 o = {x.x - mean, x.y - mean, x.z - mean, x.w - mean};
    ((float4*)dst)[tid] = o;
  }
}

// =======================================================================
// K0b: transpose weights, subtract row-mean, cast f16.
// =======================================================================
__global__ __launch_bounds__(256) void wprep_trans(
    const float* __restrict__ Wq, const float* __restrict__ Wk,
    const float* __restrict__ Wv, const float* __restrict__ Wo,
    const float* __restrict__ wmean, u16* __restrict__ wqkvt, u16* __restrict__ wot) {
  __shared__ float tl[64][65];
  const int tj = blockIdx.x, ti = blockIdx.y, m = blockIdx.z;
  const int tid = threadIdx.x;
  const float* Wm = (m == 0) ? Wq : (m == 1) ? Wk : (m == 2) ? Wv : Wo;
  const int d0 = ti * 64, h0 = tj * 64;
  #pragma unroll
  for (int rr = 0; rr < 4; ++rr) {
    const int r = (tid >> 4) + rr * 16;
    float4 x = *(const float4*)(Wm + (size_t)(d0 + r) * 1024 + h0 + ((tid & 15) << 2));
    const float mu = wmean[m * 1024 + d0 + r];
    tl[r][(tid & 15) * 4 + 0] = x.x - mu;
    tl[r][(tid & 15) * 4 + 1] = x.y - mu;
    tl[r][(tid & 15) * 4 + 2] = x.z - mu;
    tl[r][(tid & 15) * 4 + 3] = x.w - mu;
  }
  __syncthreads();
  #pragma unroll
  for (int rr = 0; rr < 2; ++rr) {
    const int hh = (tid >> 3) + rr * 32;
    const int cd = (tid & 7) << 3;
    short8_t v;
    #pragma unroll
    for (int i = 0; i < 8; ++i) v[i] = (short)f2h(tl[cd + i][hh]);
    u16* dst = (m < 3) ? (wqkvt + ((size_t)(m * 1024 + h0 + hh)) * 1024 + d0 + cd)
                       : (wot + ((size_t)(h0 + hh)) * 1024 + d0 + cd);
    *(short8_t*)dst = v;
  }
}

// =======================================================================
// K1: CLR: z = log(p+eps) - rowmean, f16   (one block per row)
// =======================================================================
__global__ __launch_bounds__(256) void clr_kernel(const float* __restrict__ p, u16* __restrict__ z) {
  __shared__ float sb[4];
  const int r = blockIdx.x, tid = threadIdx.x;
  float4 x = ((const float4*)(p + (size_t)r * 1024))[tid];
  float l0 = __logf(x.x + CLR_EPS), l1 = __logf(x.y + CLR_EPS);
  float l2 = __logf(x.z + CLR_EPS), l3 = __logf(x.w + CLR_EPS);
  float s = l0 + l1 + l2 + l3;
  #pragma unroll
  for (int dd = 32; dd; dd >>= 1) s += __shfl_xor(s, dd);
  if ((tid & 63) == 0) sb[tid >> 6] = s;
  __syncthreads();
  const float mu = (sb[0] + sb[1] + sb[2] + sb[3]) * (1.f / 1024.f);
  ushort4 o;
  o.x = f2h(l0 - mu); o.y = f2h(l1 - mu); o.z = f2h(l2 - mu); o.w = f2h(l3 - mu);
  ((ushort4*)(z + (size_t)r * 1024))[tid] = o;
}

// =======================================================================
// K2: QKV GEMM, 8-phase 256x256, f16, stage-early ledger (unchanged R10).
// =======================================================================
__global__ __launch_bounds__(512, 2) void gemm_qkv_8ph(
    const u16* __restrict__ A, const u16* __restrict__ Bt, const float* __restrict__ bias,
    u16* __restrict__ qkv, u16* __restrict__ vt) {
  __shared__ u16 As[2][256 * 64];
  __shared__ u16 Bs[2][256 * 64];
  const int tid = threadIdx.x, lane = tid & 63, wid = tid >> 6;
  const int wm = wid >> 2, wn = wid & 3;
  const int id = blockIdx.x;
  const int nid = (id & 7) * 24 + (id >> 3);
  const int m0 = (nid / 12) * 256, n0 = (nid % 12) * 256;
  const int srow = tid >> 3, schk = tid & 7;
  const int l15 = lane & 15, lg4 = (lane >> 4) << 2;

  f32x4 acc[8][4] = {};

  // ---- prologue: tile 0 fully staged ----
  stage2(Bt, n0, srow, srow + 64, 0, schk, &Bs[0][0]);
  stage2(Bt, n0, srow + 128, srow + 192, 0, schk, &Bs[0][0]);
  stage2(A, m0, srow, srow + 128, 0, schk, &As[0][0]);
  stage2(A, m0, srow + 64, srow + 192, 0, schk, &As[0][0]);
  asm volatile("s_waitcnt vmcnt(0)" ::: "memory");
  __builtin_amdgcn_s_barrier();

  short8_t afr[4], bfr[4];
  for (int t = 0; t < 16; ++t) {
    const int cur = t & 1;
    const int k0n = ((t + 1) & 15) * 64;        // wraps to 0 on last iter (dummy)
    const u16* Ab = &As[cur][0];
    const u16* Bb_ = &Bs[cur][0];
    u16* Asn = &As[cur ^ 1][0];
    u16* Bsn = &Bs[cur ^ 1][0];

    // ---------- P1: (mh0, kh0); stage B(t+1) ----------
    #pragma unroll
    for (int j = 0; j < 4; ++j) bfr[j] = ldfrag(Bb_, wn * 64 + j * 16 + l15, 0, lane);
    #pragma unroll
    for (int i = 0; i < 4; ++i) afr[i] = ldfrag(Ab, wm * 128 + i * 16 + l15, 0, lane);
    stage2(Bt, n0, srow, srow + 64, k0n, schk, Bsn);
    stage2(Bt, n0, srow + 128, srow + 192, k0n, schk, Bsn);
    __builtin_amdgcn_s_barrier();
    asm volatile("s_waitcnt lgkmcnt(0)" ::: "memory");
    __builtin_amdgcn_sched_barrier(0);
    __builtin_amdgcn_s_setprio(1);
    #pragma unroll
    for (int i = 0; i < 4; ++i)
      #pragma unroll
      for (int j = 0; j < 4; ++j)
        acc[i][j] = mfma16(afr[i], bfr[j], acc[i][j]);
    __builtin_amdgcn_s_setprio(0);
    __builtin_amdgcn_s_barrier();

    // ---------- P2: (mh1, kh0), B kh0 frags reused; stage A(t+1) ----------
    #pragma unroll
    for (int i = 0; i < 4; ++i) afr[i] = ldfrag(Ab, wm * 128 + 64 + i * 16 + l15, 0, lane);
    stage2(A, m0, srow, srow + 128, k0n, schk, Asn);
    stage2(A, m0, srow + 64, srow + 192, k0n, schk, Asn);
    __builtin_amdgcn_s_barrier();
    asm volatile("s_waitcnt lgkmcnt(0)" ::: "memory");
    __builtin_amdgcn_sched_barrier(0);
    __builtin_amdgcn_s_setprio(1);
    #pragma unroll
    for (int i = 0; i < 4; ++i)
      #pragma unroll
      for (int j = 0; j < 4; ++j)
        acc[4 + i][j] = mfma16(afr[i], bfr[j], acc[4 + i][j]);
    __builtin_amdgcn_s_setprio(0);
    __builtin_amdgcn_s_barrier();

    // ---------- P3: (mh0, kh1) ----------
    #pragma unroll
    for (int j = 0; j < 4; ++j) bfr[j] = ldfrag(Bb_, wn * 64 + j * 16 + l15, 1, lane);
    #pragma unroll
    for (int i = 0; i < 4; ++i) afr[i] = ldfrag(Ab, wm * 128 + i * 16 + l15, 1, lane);
    __builtin_amdgcn_s_barrier();
    asm volatile("s_waitcnt lgkmcnt(0)" ::: "memory");
    __builtin_amdgcn_sched_barrier(0);
    __builtin_amdgcn_s_setprio(1);
    #pragma unroll
    for (int i = 0; i < 4; ++i)
      #pragma unroll
      for (int j = 0; j < 4; ++j)
        acc[i][j] = mfma16(afr[i], bfr[j], acc[i][j]);
    __builtin_amdgcn_s_setprio(0);
    __builtin_amdgcn_s_barrier();

    // ---------- P4: (mh1, kh1); gate tile t+1 (issued 2.5 phases ago) ----------
    #pragma unroll
    for (int i = 0; i < 4; ++i) afr[i] = ldfrag(Ab, wm * 128 + 64 + i * 16 + l15, 1, lane);
    asm volatile("s_waitcnt vmcnt(0)" ::: "memory");
    __builtin_amdgcn_s_barrier();
    asm volatile("s_waitcnt lgkmcnt(0)" ::: "memory");
    __builtin_amdgcn_sched_barrier(0);
    __builtin_amdgcn_s_setprio(1);
    #pragma unroll
    for (int i = 0; i < 4; ++i)
      #pragma unroll
      for (int j = 0; j < 4; ++j)
        acc[4 + i][j] = mfma16(afr[i], bfr[j], acc[4 + i][j]);
    __builtin_amdgcn_s_setprio(0);
    __builtin_amdgcn_s_barrier();
  }

  // ---- epilogue ----
  if (n0 < 2048) {
    const float sc = (n0 < 1024) ? QSCALE_CONST : 1.0f;   // Q cols get log2(e)/8
    #pragma unroll
    for (int j = 0; j < 4; ++j) {
      const int col = n0 + wn * 64 + j * 16 + l15;
      const float bb = bias[col];
      #pragma unroll
      for (int i = 0; i < 8; ++i) {
        const int rowb = m0 + wm * 128 + i * 16 + lg4;
        #pragma unroll
        for (int r = 0; r < 4; ++r)
          qkv[(size_t)(rowb + r) * 3072 + col] = f2h((acc[i][j][r] + bb) * sc);
      }
    }
  } else {
    // V third: transposed + key-permuted into vt[(b*16+h)*64+dk][pos(t)]
    const int h = (n0 - 2048 + wn * 64) >> 6;
    #pragma unroll
    for (int j = 0; j < 4; ++j) {
      const int dk = j * 16 + l15;
      const float bb = bias[n0 + wn * 64 + dk];
      #pragma unroll
      for (int i = 0; i < 8; ++i) {
        const int rowb = m0 + wm * 128 + i * 16 + lg4;   // global M row (mult of 4)
        const int b = rowb >> 11, tq = rowb & 2047;
        const int k5 = tq & 31;                          // low 2 bits are 0
        const int pos = (tq & ~31) + (k5 & 16) + ((k5 & 4) << 1) + ((k5 & 8) >> 1);
        ushort4 pk;
        pk.x = f2h(acc[i][j][0] + bb);
        pk.y = f2h(acc[i][j][1] + bb);
        pk.z = f2h(acc[i][j][2] + bb);
        pk.w = f2h(acc[i][j][3] + bb);
        *(ushort4*)(vt + ((size_t)((b * NHEAD + h) * 64 + dk)) * TT + pos) = pk;
      }
    }
  }
}

// =======================================================================
// K5: f16 GEMM (out-proj, f32 out), 128x128 — dbuf stage-early (bit-exact
//  scheduling change vs R10: same frag order/MFMA order; staging of tile
//  t+1 issued at top of iter t, single vmcnt(0)+barrier per iter instead
//  of serial stage -> drain -> compute with 2 barriers).
// =======================================================================
__global__ __launch_bounds__(256) void gemm_bt(
    const u16* __restrict__ A, const u16* __restrict__ Bt, const float* __restrict__ bias,
    float* __restrict__ Cout, int Ndim, int Kdim) {
  __shared__ u16 As[2][128 * 64];
  __shared__ u16 Bs[2][128 * 64];
  const int tid = threadIdx.x;
  const int lane = tid & 63, wid = tid >> 6;
  const int m0 = blockIdx.y * 128, n0 = blockIdx.x * 128;
  const int wm = wid >> 1, wn = wid & 1;
  const int srow = tid >> 3, schk = tid & 7;
  f32x4 acc[4][4] = {};

  auto STG = [&](int k0, int buf) {
    #pragma unroll
    for (int rr = 0; rr < 4; ++rr) {
      const int row = srow + rr * 32;
      const int gcol = k0 + ((schk ^ (row & 7)) << 3);
      async16(A + (size_t)(m0 + row) * Kdim + gcol, &As[buf][row * 64 + schk * 8]);
      async16(Bt + (size_t)(n0 + row) * Kdim + gcol, &Bs[buf][row * 64 + schk * 8]);
    }
  };

  STG(0, 0);
  asm volatile("s_waitcnt vmcnt(0)" ::: "memory");
  __builtin_amdgcn_s_barrier();

  const int nt = Kdim >> 6;           // 16 for K=1024
  for (int t = 0; t < nt; ++t) {
    const int cur = t & 1;
    STG((((t + 1) & (nt - 1))) << 6, cur ^ 1);   // wraps -> dummy on last iter
    #pragma unroll
    for (int kk = 0; kk < 2; ++kk) {
      short8_t af[4], bf[4];
      #pragma unroll
      for (int i = 0; i < 4; ++i) {
        af[i] = ldfrag(&As[cur][0], wm * 64 + i * 16 + (lane & 15), kk, lane);
        bf[i] = ldfrag(&Bs[cur][0], wn * 64 + i * 16 + (lane & 15), kk, lane);
      }
      #pragma unroll
      for (int i = 0; i < 4; ++i)
        #pragma unroll
        for (int j = 0; j < 4; ++j)
          acc[i][j] = mfma16(af[i], bf[j], acc[i][j]);
    }
    asm volatile("s_waitcnt vmcnt(0)" ::: "memory");  // tile t+1 landed (issued ~600cy ago)
    __builtin_amdgcn_s_barrier();                     // all reads of buf cur done
  }

  #pragma unroll
  for (int j = 0; j < 4; ++j) {
    const int col = n0 + wn * 64 + j * 16 + (lane & 15);
    const float bb = bias[col];
    #pragma unroll
    for (int i = 0; i < 4; ++i) {
      const int rowb = m0 + wm * 64 + i * 16 + ((lane >> 4) << 2);
      #pragma unroll
      for (int r = 0; r < 4; ++r)
        Cout[(size_t)(rowb + r) * Ndim + col] = acc[i][j][r] + bb;
    }
  }
}

// =======================================================================
// K4: flash attention (R10 structure, f16). XCD-grouped decode: the 8
//  q-blocks of one (b,h) share id%8 (= XCD under default round-robin) so
//  that (b,h)'s 512KB K/V stream stays in ONE L2 (4 pairs = 2MB per XCD).
//  Pure block remap -- bit-exact vs R10.
// =======================================================================
__global__ __launch_bounds__(512, 2) void attn_kernel(
    const u16* __restrict__ qkv, const u16* __restrict__ vt, u16* __restrict__ zout) {
  __shared__ char smem[65536];   // [0,32K): K[stream][buf]; [32K,64K): V[stream][buf]
  const int id = blockIdx.x;
  const int qb = (id >> 3) & 7;
  const int bh = (id & 7) * 4 + (id >> 6);    // id%8 = XCD owns 4 (b,h) pairs
  const int b = bh >> 4, h = bh & 15;
  const int tid = threadIdx.x, lane = tid & 63, w = tid >> 6;
  const int qw = w & 3, ks = w >> 2;
  const int hl = lane >> 5, l31 = lane & 31;
  const int swz = (l31 & 7) << 4;
  const int q0 = qb * 256 + qw * 64;

  // ---- Q B-frags from global: qf[qt][c] elem j = Q[q0+qt*32+l31][c*16+hl*8+j] ----
  short8_t qf[2][4];
  #pragma unroll
  for (int qt = 0; qt < 2; ++qt)
    #pragma unroll
    for (int c = 0; c < 4; ++c)
      qf[qt][c] = *(const short8_t*)(qkv + (size_t)(b * TT + q0 + qt * 32 + l31) * 3072
                                     + h * 64 + c * 16 + hl * 8);

  // ---- staging geometry: stream's 4 waves cover rows 0..63 (wave qw: 16 rows) ----
  const int sr0 = qw * 16 + (lane >> 3);      // and sr0+8
  const int schk = lane & 7;
  const int scol = (schk ^ (sr0 & 7)) << 3;   // inverse-swizzled source col (elems)
  const int dof = sr0 * 128 + schk * 16;      // LDS byte offset within a tile
  char* kls = smem + ks * 16384;              // this stream's K bufs (+0 / +8192)
  char* vls = smem + 32768 + ks * 16384;
  const u16* kg = qkv + 1024 + (size_t)h * 64;
  const u16* vg = vt + ((size_t)(b * NHEAD + h) * 64 + sr0) * (size_t)TT;

  // prologue: stage tile 0
  {
    const int kbase = ks * 1024;
    async16(kg + (size_t)(b * TT + kbase + sr0) * 3072 + scol, kls + dof);
    async16(kg + (size_t)(b * TT + kbase + sr0 + 8) * 3072 + scol, kls + dof + 1024);
    async16(vg + kbase + scol, vls + dof);
    async16(vg + (size_t)8 * TT + kbase + scol, vls + dof + 1024);
  }

  f32x16 o[2][2] = {};
  f32x16 lb[2] = {};
  short8_t ones;
  #pragma unroll
  for (int i = 0; i < 8; ++i) ones[i] = (short)0x3C00;   // f16 1.0

  for (int it = 0; it < 16; ++it) {
    __syncthreads();                  // buf[it&1] staged; prior compute done
    if (it < 15) {
      const int kbase = ks * 1024 + (it + 1) * 64;
      const int bo = ((it + 1) & 1) * 8192;
      async16(kg + (size_t)(b * TT + kbase + sr0) * 3072 + scol, kls + bo + dof);
      async16(kg + (size_t)(b * TT + kbase + sr0 + 8) * 3072 + scol, kls + bo + dof + 1024);
      async16(vg + kbase + scol, vls + bo + dof);
      async16(vg + (size_t)8 * TT + kbase + scol, vls + bo + dof + 1024);
    }
    const char* Kb = kls + (it & 1) * 8192;
    const char* Vb = vls + (it & 1) * 8192;

    #pragma unroll
    for (int kt = 0; kt < 2; ++kt) {
      // ---- S^T = K Q^T (2 q-tiles share each K fragment) ----
      f32x16 s[2] = {};
      #pragma unroll
      for (int c = 0; c < 4; ++c) {
        const int krow = kt * 32 + l31;
        const short8_t kfr = *(const short8_t*)(Kb + krow * 128 + ((c * 32 + hl * 16) ^ swz));
        s[0] = mfma32(kfr, qf[0][c], s[0]);
        s[1] = mfma32(kfr, qf[1][c], s[1]);
      }
      // ---- P = 2^S in-register ----
      #pragma unroll
      for (int qt = 0; qt < 2; ++qt)
        #pragma unroll
        for (int r = 0; r < 16; ++r) {
          float pv;
          asm("v_exp_f32 %0, %1" : "=v"(pv) : "v"(s[qt][r]));
          s[qt][r] = pv;
        }
      // ---- pack to PV A-frags, l-MFMA, PV (V frags single b128, permuted keys) ----
      #pragma unroll
      for (int cc = 0; cc < 2; ++cc) {
        short8_t pa[2];
        #pragma unroll
        for (int qt = 0; qt < 2; ++qt) {
          int w0 = __builtin_bit_cast(int, __builtin_amdgcn_cvt_pkrtz(s[qt][8 * cc + 0], s[qt][8 * cc + 1]));
          int w1 = __builtin_bit_cast(int, __builtin_amdgcn_cvt_pkrtz(s[qt][8 * cc + 2], s[qt][8 * cc + 3]));
          int w2 = __builtin_bit_cast(int, __builtin_amdgcn_cvt_pkrtz(s[qt][8 * cc + 4], s[qt][8 * cc + 5]));
          int w3 = __builtin_bit_cast(int, __builtin_amdgcn_cvt_pkrtz(s[qt][8 * cc + 6], s[qt][8 * cc + 7]));
          int4v fw = {w0, w1, w2, w3};
          pa[qt] = __builtin_bit_cast(short8_t, fw);
          lb[qt] = mfma32(pa[qt], ones, lb[qt]);
        }
        const int cb = kt * 64 + cc * 32 + hl * 16;   // byte offset of pos-group
        #pragma unroll
        for (int dkt = 0; dkt < 2; ++dkt) {
          const int vrow = dkt * 32 + l31;
          const short8_t vfr = *(const short8_t*)(Vb + vrow * 128 + (cb ^ swz));
          o[0][dkt] = mfma32(pa[0], vfr, o[0][dkt]);
          o[1][dkt] = mfma32(pa[1], vfr, o[1][dkt]);
        }
      }
    }
  }

  // ---- cross-stream reduction through (now dead) staging LDS ----
  __syncthreads();                    // all LDS reads of the main loop done
  const int slot = qw * 64 + lane;    // 256 slots
  if (ks == 1) {
    u16* ro = (u16*)(smem + slot * 136);            // 64 f16, stride-padded
    #pragma unroll
    for (int qt = 0; qt < 2; ++qt)
      #pragma unroll
      for (int dkt = 0; dkt < 2; ++dkt)
        #pragma unroll
        for (int r = 0; r < 16; ++r)
          ro[(qt * 2 + dkt) * 16 + r] = f2h(o[qt][dkt][r]);
    u16* rl = (u16*)(smem + 36864 + slot * 72);     // 32 f16
    #pragma unroll
    for (int qt = 0; qt < 2; ++qt)
      #pragma unroll
      for (int r = 0; r < 16; ++r)
        rl[qt * 16 + r] = f2h(lb[qt][r]);
  }
  __syncthreads();
  if (ks == 0) {
    const u16* ro = (const u16*)(smem + slot * 136);
    const u16* rl = (const u16*)(smem + 36864 + slot * 72);
    #pragma unroll
    for (int qt = 0; qt < 2; ++qt) {
      #pragma unroll
      for (int r = 0; r < 16; ++r) lb[qt][r] += h2f(rl[qt * 16 + r]);
      #pragma unroll
      for (int dkt = 0; dkt < 2; ++dkt)
        #pragma unroll
        for (int r = 0; r < 16; ++r) o[qt][dkt][r] += h2f(ro[(qt * 2 + dkt) * 16 + r]);
    }
    #pragma unroll
    for (int qt = 0; qt < 2; ++qt) {
      float rlv[16];
      #pragma unroll
      for (int r = 0; r < 16; ++r) rlv[r] = 1.f / lb[qt][r];
      #pragma unroll
      for (int dkt = 0; dkt < 2; ++dkt) {
        const int col = h * 64 + dkt * 32 + l31;
        #pragma unroll
        for (int r = 0; r < 16; ++r) {
          const int rowg = b * TT + q0 + qt * 32 + (r & 3) + 8 * (r >> 2) + 4 * hl;
          zout[(size_t)rowg * 1024 + col] = f2h(o[qt][dkt][r] * rlv[r]);
        }
      }
    }
  }
}

// =======================================================================
// K6: final row softmax (logits f32 [4096][1024] -> out f32)
// =======================================================================
__global__ __launch_bounds__(256) void softmax_rows(const float* __restrict__ logits,
                                                    float* __restrict__ out) {
  __shared__ float sb[8];
  const int r = blockIdx.x, tid = threadIdx.x;
  float4 x = ((const float4*)(logits + (size_t)r * 1024))[tid];
  float mx = fmaxf(fmaxf(x.x, x.y), fmaxf(x.z, x.w));
  #pragma unroll
  for (int dd = 32; dd; dd >>= 1) mx = fmaxf(mx, __shfl_xor(mx, dd));
  if ((tid & 63) == 0) sb[tid >> 6] = mx;
  __syncthreads();
  mx = fmaxf(fmaxf(sb[0], sb[1]), fmaxf(sb[2], sb[3]));
  const float e0 = __expf(x.x - mx), e1 = __expf(x.y - mx);
  const float e2 = __expf(x.z - mx), e3 = __expf(x.w - mx);
  float s = e0 + e1 + e2 + e3;
  #pragma unroll
  for (int dd = 32; dd; dd >>= 1) s += __shfl_xor(s, dd);
  __syncthreads();
  if ((tid & 63) == 0) sb[4 + (tid >> 6)] = s;
  __syncthreads();
  s = sb[4] + sb[5] + sb[6] + sb[7];
  const float inv = 1.f / s;
  float4 o = {e0 * inv, e1 * inv, e2 * inv, e3 * inv};
  ((float4*)(out + (size_t)r * 1024))[tid] = o;
}

// =======================================================================
extern "C" void kernel_launch(void* const* d_in, const int* in_sizes, int n_in,
                              void* d_out, int out_size, void* d_ws, size_t ws_size,
                              hipStream_t stream) {
  (void)in_sizes; (void)n_in; (void)out_size; (void)ws_size;
  const float* p  = (const float*)d_in[0];
  const float* Wq = (const float*)d_in[1];
  const float* bq = (const float*)d_in[2];
  const float* Wk = (const float*)d_in[3];
  const float* bk = (const float*)d_in[4];
  const float* Wv = (const float*)d_in[5];
  const float* bv = (const float*)d_in[6];
  const float* Wo = (const float*)d_in[7];
  const float* bo = (const float*)d_in[8];
  float* out = (float*)d_out;

  char* ws = (char*)d_ws;
  u16*   wqkvt  = (u16*)(ws + O_WQKVT);
  u16*   wot    = (u16*)(ws + O_WOT);
  float* wmean  = (float*)(ws + O_WMEAN);
  float* bqkv_p = (float*)(ws + O_BQKV);
  float* bo_p   = (float*)(ws + O_BO);
  u16*   z      = (u16*)(ws + O_Z);
  u16*   qkv    = (u16*)(ws + O_QKV);
  u16*   vt     = (u16*)(ws + O_VT);
  u16*   zoutb  = (u16*)(ws + O_ZOUT);
  float* logits = (float*)(ws + O_LOGITS);

  wprep_mean<<<4100, 256, 0, stream>>>(Wq, Wk, Wv, Wo, bq, bk, bv, bo, wmean, bqkv_p, bo_p);
  wprep_trans<<<dim3(16, 16, 4), 256, 0, stream>>>(Wq, Wk, Wv, Wo, wmean, wqkvt, wot);
  clr_kernel<<<MR, 256, 0, stream>>>(p, z);
  gemm_qkv_8ph<<<192, 512, 0, stream>>>(z, wqkvt, bqkv_p, qkv, vt);
  attn_kernel<<<256, 512, 0, stream>>>(qkv, vt, zoutb);
  gemm_bt<<<dim3(1024 / 128, MR / 128), 256, 0, stream>>>(zoutb, wot, bo_p, logits, 1024, 1024);
  softmax_rows<<<MR, 256, 0, stream>>>(logits, out);
}

// Round 13
// 128.308 us; speedup vs baseline: 1.0556x; 1.0556x over previous
//
#include <hip/hip_runtime.h>

typedef unsigned short u16;
typedef __attribute__((ext_vector_type(8))) short short8_t;     // 8 x f16 payload (4 VGPR)
typedef __attribute__((ext_vector_type(8))) _Float16 half8_t;   // MFMA f16 operand
typedef __attribute__((ext_vector_type(4))) float f32x4;        // 16x16 MFMA accum
typedef __attribute__((ext_vector_type(16))) float f32x16;      // 32x32 MFMA accum
typedef __attribute__((ext_vector_type(4))) int int4v;

// ---- problem dims ----
#define BB    2
#define TT    2048
#define DD    1024
#define NHEAD 16
#define DKH   64
#define HH    1024
#define MR    4096          // B*T
#define CLR_EPS 1e-6f
// log2(e)/8 folded into Q so P = 2^(q'.k) = exp(q.k/8)
#define QSCALE_CONST 0.18033688011112042f

// ---- workspace byte offsets ----
#define O_WQKVT  0ull                 // f16 [3072][1024]
#define O_WOT    6291456ull           // f16 [1024][1024]
#define O_WMEAN  8388608ull           // f32  [4][1024]
#define O_BQKV   8404992ull           // f32  [3072]
#define O_BO     8417280ull           // f32  [1024]
#define O_Z      8421376ull           // f16 [4096][1024]
#define O_QKV    16809984ull          // f16 [4096][3072]  (q|k cols; v third unused)
#define O_VT     41975808ull          // f16 [B*NH][64][2048]  (keys PERMUTED within 32-groups)
#define O_ZOUT   50364416ull          // f16 [4096][1024]
#define O_LOGITS O_QKV                // f32  [4096][1024] (reuses dead qkv region)

// ---------------- helpers ----------------
__device__ __forceinline__ u16 f2h(float f) {
  _Float16 h = (_Float16)f;           // v_cvt_f16_f32 (RNE)
  return __builtin_bit_cast(u16, h);
}
__device__ __forceinline__ float h2f(u16 x) {
  return (float)__builtin_bit_cast(_Float16, x);
}

__device__ __forceinline__ f32x4 mfma16(short8_t a, short8_t b, f32x4 c) {
  return __builtin_amdgcn_mfma_f32_16x16x32_f16(
      __builtin_bit_cast(half8_t, a), __builtin_bit_cast(half8_t, b), c, 0, 0, 0);
}
__device__ __forceinline__ f32x16 mfma32(short8_t a, short8_t b, f32x16 c) {
  return __builtin_amdgcn_mfma_f32_32x32x16_f16(
      __builtin_bit_cast(half8_t, a), __builtin_bit_cast(half8_t, b), c, 0, 0, 0);
}

typedef const __attribute__((address_space(1))) unsigned int as1_u32_t;
typedef __attribute__((address_space(3))) unsigned int as3_u32_t;

__device__ __forceinline__ void async16(const void* g, void* l) {
  __builtin_amdgcn_global_load_lds((as1_u32_t*)g, (as3_u32_t*)l, 16, 0, 0);
}

// swizzled ds_read of one 16x16x32 A/B fragment from a [*][64] f16 tile
__device__ __forceinline__ short8_t ldfrag(const u16* buf, int row, int kh, int lane) {
  const int byte = (row * 128 + ((kh * 32 + ((lane >> 4) << 3)) << 1)) ^ ((row & 7) << 4);
  return *(const short8_t*)((const char*)buf + byte);
}

// =======================================================================
// K0a: weight row-means (mean over out-dim h for each in-dim d) + biases
// =======================================================================
__global__ __launch_bounds__(256) void wprep_mean(
    const float* __restrict__ Wq, const float* __restrict__ Wk,
    const float* __restrict__ Wv, const float* __restrict__ Wo,
    const float* __restrict__ bq, const float* __restrict__ bk,
    const float* __restrict__ bv, const float* __restrict__ bo,
    float* __restrict__ wmean, float* __restrict__ bqkv_p, float* __restrict__ bo_p) {
  __shared__ float sb[4];
  const int bid = blockIdx.x, tid = threadIdx.x;
  if (bid < 4096) {
    const int m = bid >> 10, d = bid & 1023;
    const float* Wm = (m == 0) ? Wq : (m == 1) ? Wk : (m == 2) ? Wv : Wo;
    float4 x = ((const float4*)(Wm + (size_t)d * 1024))[tid];
    float s = x.x + x.y + x.z + x.w;
    #pragma unroll
    for (int dd = 32; dd; dd >>= 1) s += __shfl_xor(s, dd);
    if ((tid & 63) == 0) sb[tid >> 6] = s;
    __syncthreads();
    if (tid == 0) wmean[bid] = (sb[0] + sb[1] + sb[2] + sb[3]) * (1.f / 1024.f);
  } else {
    const int j = bid - 4096;
    const float* bb = (j == 0) ? bq : (j == 1) ? bk : (j == 2) ? bv : bo;
    float4 x = ((const float4*)bb)[tid];
    float s = x.x + x.y + x.z + x.w;
    #pragma unroll
    for (int dd = 32; dd; dd >>= 1) s += __shfl_xor(s, dd);
    if ((tid & 63) == 0) sb[tid >> 6] = s;
    __syncthreads();
    const float mean = (sb[0] + sb[1] + sb[2] + sb[3]) * (1.f / 1024.f);
    float* dst = (j < 3) ? (bqkv_p + j * 1024) : bo_p;
    float4 o = {x.x - mean, x.y - mean, x.z - mean, x.w - mean};
    ((float4*)dst)[tid] = o;
  }
}

// =======================================================================
// K0b: transpose weights, subtract row-mean, cast f16.
// =======================================================================
__global__ __launch_bounds__(256) void wprep_trans(
    const float* __restrict__ Wq, const float* __restrict__ Wk,
    const float* __restrict__ Wv, const float* __restrict__ Wo,
    const float* __restrict__ wmean, u16* __restrict__ wqkvt, u16* __restrict__ wot) {
  __shared__ float tl[64][65];
  const int tj = blockIdx.x, ti = blockIdx.y, m = blockIdx.z;
  const int tid = threadIdx.x;
  const float* Wm = (m == 0) ? Wq : (m == 1) ? Wk : (m == 2) ? Wv : Wo;
  const int d0 = ti * 64, h0 = tj * 64;
  #pragma unroll
  for (int rr = 0; rr < 4; ++rr) {
    const int r = (tid >> 4) + rr * 16;
    float4 x = *(const float4*)(Wm + (size_t)(d0 + r) * 1024 + h0 + ((tid & 15) << 2));
    const float mu = wmean[m * 1024 + d0 + r];
    tl[r][(tid & 15) * 4 + 0] = x.x - mu;
    tl[r][(tid & 15) * 4 + 1] = x.y - mu;
    tl[r][(tid & 15) * 4 + 2] = x.z - mu;
    tl[r][(tid & 15) * 4 + 3] = x.w - mu;
  }
  __syncthreads();
  #pragma unroll
  for (int rr = 0; rr < 2; ++rr) {
    const int hh = (tid >> 3) + rr * 32;
    const int cd = (tid & 7) << 3;
    short8_t v;
    #pragma unroll
    for (int i = 0; i < 8; ++i) v[i] = (short)f2h(tl[cd + i][hh]);
    u16* dst = (m < 3) ? (wqkvt + ((size_t)(m * 1024 + h0 + hh)) * 1024 + d0 + cd)
                       : (wot + ((size_t)(h0 + hh)) * 1024 + d0 + cd);
    *(short8_t*)dst = v;
  }
}

// =======================================================================
// K1: CLR: z = log(p+eps) - rowmean, f16   (one block per row)
// =======================================================================
__global__ __launch_bounds__(256) void clr_kernel(const float* __restrict__ p, u16* __restrict__ z) {
  __shared__ float sb[4];
  const int r = blockIdx.x, tid = threadIdx.x;
  float4 x = ((const float4*)(p + (size_t)r * 1024))[tid];
  float l0 = __logf(x.x + CLR_EPS), l1 = __logf(x.y + CLR_EPS);
  float l2 = __logf(x.z + CLR_EPS), l3 = __logf(x.w + CLR_EPS);
  float s = l0 + l1 + l2 + l3;
  #pragma unroll
  for (int dd = 32; dd; dd >>= 1) s += __shfl_xor(s, dd);
  if ((tid & 63) == 0) sb[tid >> 6] = s;
  __syncthreads();
  const float mu = (sb[0] + sb[1] + sb[2] + sb[3]) * (1.f / 1024.f);
  ushort4 o;
  o.x = f2h(l0 - mu); o.y = f2h(l1 - mu); o.z = f2h(l2 - mu); o.w = f2h(l3 - mu);
  ((ushort4*)(z + (size_t)r * 1024))[tid] = o;
}

// =======================================================================
// K2 v3: QKV GEMM, f16, 128x192 tile, BK=64, 4 waves (2x2, 64x96/wave),
//  LDS 80KB -> grid 512 = 2 blocks/CU (independent blocks overlap each
//  other's LDS-read/barrier phases; m114). 2 phases per K-tile, stage-early
//  (tile t+1 issued in P1), single vmcnt(0) after P2's MFMA. XCD-grouped
//  8x8 tile sub-grids. Per-output K-accumulation order unchanged vs R11.
// =======================================================================
__global__ __launch_bounds__(256, 2) void gemm_qkv_8ph(
    const u16* __restrict__ A, const u16* __restrict__ Bt, const float* __restrict__ bias,
    u16* __restrict__ qkv, u16* __restrict__ vt) {
  __shared__ u16 As[2][128 * 64];   // 32 KB
  __shared__ u16 Bs[2][192 * 64];   // 48 KB
  const int tid = threadIdx.x, lane = tid & 63, w = tid >> 6;
  const int wm = w >> 1, wn = w & 1;          // wave tile 64x96
  // XCD-grouped decode: XCD x owns an 8x8 sub-grid of (m,n) tiles.
  const int id = blockIdx.x;
  const int x = id & 7, idx = id >> 3;        // idx 0..63
  const int mt = (x & 3) * 8 + (idx & 7);     // 0..31
  const int nt = (x >> 2) * 8 + (idx >> 3);   // 0..15
  const int m0 = mt * 128, n0 = nt * 192;
  const int srow = tid >> 3, schk = tid & 7;  // staging: 32 rows/round
  const int l15 = lane & 15, lg4 = (lane >> 4) << 2;

  f32x4 acc[4][6] = {};

  auto stA = [&](int k0, int buf) {
    #pragma unroll
    for (int u = 0; u < 4; ++u) {
      const int r = srow + u * 32;
      const int c = k0 + ((schk ^ (r & 7)) << 3);
      async16(A + (size_t)(m0 + r) * 1024 + c, &As[buf][r * 64 + schk * 8]);
    }
  };
  auto stB = [&](int k0, int buf) {
    #pragma unroll
    for (int u = 0; u < 6; ++u) {
      const int r = srow + u * 32;
      const int c = k0 + ((schk ^ (r & 7)) << 3);
      async16(Bt + (size_t)(n0 + r) * 1024 + c, &Bs[buf][r * 64 + schk * 8]);
    }
  };

  // prologue: tile 0
  stA(0, 0); stB(0, 0);
  asm volatile("s_waitcnt vmcnt(0)" ::: "memory");
  __builtin_amdgcn_s_barrier();

  short8_t afr[4], bfr[6];
  for (int t = 0; t < 16; ++t) {
    const int cur = t & 1;
    const int k0n = ((t + 1) & 15) * 64;      // wraps to 0 on last iter (dummy)
    const u16* Ab = &As[cur][0];
    const u16* Bb_ = &Bs[cur][0];

    // ---------- P1 (kh0): read frags, stage tile t+1 ----------
    #pragma unroll
    for (int j = 0; j < 6; ++j) bfr[j] = ldfrag(Bb_, wn * 96 + j * 16 + l15, 0, lane);
    #pragma unroll
    for (int i = 0; i < 4; ++i) afr[i] = ldfrag(Ab, wm * 64 + i * 16 + l15, 0, lane);
    stA(k0n, cur ^ 1); stB(k0n, cur ^ 1);
    __builtin_amdgcn_s_barrier();
    asm volatile("s_waitcnt lgkmcnt(0)" ::: "memory");
    __builtin_amdgcn_sched_barrier(0);
    __builtin_amdgcn_s_setprio(1);
    #pragma unroll
    for (int i = 0; i < 4; ++i)
      #pragma unroll
      for (int j = 0; j < 6; ++j)
        acc[i][j] = mfma16(afr[i], bfr[j], acc[i][j]);
    __builtin_amdgcn_s_setprio(0);
    __builtin_amdgcn_s_barrier();

    // ---------- P2 (kh1): read frags; gate tile t+1 after MFMA ----------
    #pragma unroll
    for (int j = 0; j < 6; ++j) bfr[j] = ldfrag(Bb_, wn * 96 + j * 16 + l15, 1, lane);
    #pragma unroll
    for (int i = 0; i < 4; ++i) afr[i] = ldfrag(Ab, wm * 64 + i * 16 + l15, 1, lane);
    __builtin_amdgcn_s_barrier();
    asm volatile("s_waitcnt lgkmcnt(0)" ::: "memory");
    __builtin_amdgcn_sched_barrier(0);
    __builtin_amdgcn_s_setprio(1);
    #pragma unroll
    for (int i = 0; i < 4; ++i)
      #pragma unroll
      for (int j = 0; j < 6; ++j)
        acc[i][j] = mfma16(afr[i], bfr[j], acc[i][j]);
    __builtin_amdgcn_s_setprio(0);
    asm volatile("s_waitcnt vmcnt(0)" ::: "memory");  // tile t+1 landed (1.5 phases slack)
    __builtin_amdgcn_s_barrier();                     // gates next-iter reads + overwrite
  }

  // ---- epilogue: per-frag column branch (16-col frags never straddle 64-boundaries) ----
  #pragma unroll
  for (int j = 0; j < 6; ++j) {
    const int col = n0 + wn * 96 + j * 16 + l15;
    const float bb = bias[col];
    if (col < 2048) {
      const float sc = (col < 1024) ? QSCALE_CONST : 1.0f;
      #pragma unroll
      for (int i = 0; i < 4; ++i) {
        const int rowb = m0 + wm * 64 + i * 16 + lg4;
        #pragma unroll
        for (int r = 0; r < 4; ++r)
          qkv[(size_t)(rowb + r) * 3072 + col] = f2h((acc[i][j][r] + bb) * sc);
      }
    } else {
      // V: transposed + key-permuted into vt[(b*16+h)*64+dk][pos(t)]
      const int h = (col - 2048) >> 6, dk = col & 63;
      #pragma unroll
      for (int i = 0; i < 4; ++i) {
        const int rowb = m0 + wm * 64 + i * 16 + lg4;   // mult of 4
        const int b = rowb >> 11, tq = rowb & 2047;
        const int k5 = tq & 31;
        const int pos = (tq & ~31) + (k5 & 16) + ((k5 & 4) << 1) + ((k5 & 8) >> 1);
        ushort4 pk;
        pk.x = f2h(acc[i][j][0] + bb);
        pk.y = f2h(acc[i][j][1] + bb);
        pk.z = f2h(acc[i][j][2] + bb);
        pk.w = f2h(acc[i][j][3] + bb);
        *(ushort4*)(vt + ((size_t)((b * NHEAD + h) * 64 + dk)) * TT + pos) = pk;
      }
    }
  }
}

// =======================================================================
// K5: f16 GEMM (out-proj, f32 out), 128x128, dbuf stage-early (R11).
// =======================================================================
__global__ __launch_bounds__(256) void gemm_bt(
    const u16* __restrict__ A, const u16* __restrict__ Bt, const float* __restrict__ bias,
    float* __restrict__ Cout, int Ndim, int Kdim) {
  __shared__ u16 As[2][128 * 64];
  __shared__ u16 Bs[2][128 * 64];
  const int tid = threadIdx.x;
  const int lane = tid & 63, wid = tid >> 6;
  const int m0 = blockIdx.y * 128, n0 = blockIdx.x * 128;
  const int wm = wid >> 1, wn = wid & 1;
  const int srow = tid >> 3, schk = tid & 7;
  f32x4 acc[4][4] = {};

  auto STG = [&](int k0, int buf) {
    #pragma unroll
    for (int rr = 0; rr < 4; ++rr) {
      const int row = srow + rr * 32;
      const int gcol = k0 + ((schk ^ (row & 7)) << 3);
      async16(A + (size_t)(m0 + row) * Kdim + gcol, &As[buf][row * 64 + schk * 8]);
      async16(Bt + (size_t)(n0 + row) * Kdim + gcol, &Bs[buf][row * 64 + schk * 8]);
    }
  };

  STG(0, 0);
  asm volatile("s_waitcnt vmcnt(0)" ::: "memory");
  __builtin_amdgcn_s_barrier();

  const int nt = Kdim >> 6;           // 16 for K=1024
  for (int t = 0; t < nt; ++t) {
    const int cur = t & 1;
    STG((((t + 1) & (nt - 1))) << 6, cur ^ 1);   // wraps -> dummy on last iter
    #pragma unroll
    for (int kk = 0; kk < 2; ++kk) {
      short8_t af[4], bf[4];
      #pragma unroll
      for (int i = 0; i < 4; ++i) {
        af[i] = ldfrag(&As[cur][0], wm * 64 + i * 16 + (lane & 15), kk, lane);
        bf[i] = ldfrag(&Bs[cur][0], wn * 64 + i * 16 + (lane & 15), kk, lane);
      }
      #pragma unroll
      for (int i = 0; i < 4; ++i)
        #pragma unroll
        for (int j = 0; j < 4; ++j)
          acc[i][j] = mfma16(af[i], bf[j], acc[i][j]);
    }
    asm volatile("s_waitcnt vmcnt(0)" ::: "memory");  // tile t+1 landed
    __builtin_amdgcn_s_barrier();                     // all reads of buf cur done
  }

  #pragma unroll
  for (int j = 0; j < 4; ++j) {
    const int col = n0 + wn * 64 + j * 16 + (lane & 15);
    const float bb = bias[col];
    #pragma unroll
    for (int i = 0; i < 4; ++i) {
      const int rowb = m0 + wm * 64 + i * 16 + ((lane >> 4) << 2);
      #pragma unroll
      for (int r = 0; r < 4; ++r)
        Cout[(size_t)(rowb + r) * Ndim + col] = acc[i][j][r] + bb;
    }
  }
}

// =======================================================================
// K4: flash attention — R11 form VERBATIM (8 waves, 256 q-rows/block,
//  XCD-grouped decode). This structure has passed 5/5 rounds; the 4-wave
//  128-row re-block failed 3/3 at the absmax threshold. FROZEN.
// =======================================================================
__global__ __launch_bounds__(512, 2) void attn_kernel(
    const u16* __restrict__ qkv, const u16* __restrict__ vt, u16* __restrict__ zout) {
  __shared__ char smem[65536];   // [0,32K): K[stream][buf]; [32K,64K): V[stream][buf]
  const int id = blockIdx.x;
  const int qb = (id >> 3) & 7;
  const int bh = (id & 7) * 4 + (id >> 6);    // id%8 = XCD owns 4 (b,h) pairs
  const int b = bh >> 4, h = bh & 15;
  const int tid = threadIdx.x, lane = tid & 63, w = tid >> 6;
  const int qw = w & 3, ks = w >> 2;
  const int hl = lane >> 5, l31 = lane & 31;
  const int swz = (l31 & 7) << 4;
  const int q0 = qb * 256 + qw * 64;

  // ---- Q B-frags from global: qf[qt][c] elem j = Q[q0+qt*32+l31][c*16+hl*8+j] ----
  short8_t qf[2][4];
  #pragma unroll
  for (int qt = 0; qt < 2; ++qt)
    #pragma unroll
    for (int c = 0; c < 4; ++c)
      qf[qt][c] = *(const short8_t*)(qkv + (size_t)(b * TT + q0 + qt * 32 + l31) * 3072
                                     + h * 64 + c * 16 + hl * 8);

  // ---- staging geometry: stream's 4 waves cover rows 0..63 (wave qw: 16 rows) ----
  const int sr0 = qw * 16 + (lane >> 3);      // and sr0+8
  const int schk = lane & 7;
  const int scol = (schk ^ (sr0 & 7)) << 3;   // inverse-swizzled source col (elems)
  const int dof = sr0 * 128 + schk * 16;      // LDS byte offset within a tile
  char* kls = smem + ks * 16384;              // this stream's K bufs (+0 / +8192)
  char* vls = smem + 32768 + ks * 16384;
  const u16* kg = qkv + 1024 + (size_t)h * 64;
  const u16* vg = vt + ((size_t)(b * NHEAD + h) * 64 + sr0) * (size_t)TT;

  // prologue: stage tile 0
  {
    const int kbase = ks * 1024;
    async16(kg + (size_t)(b * TT + kbase + sr0) * 3072 + scol, kls + dof);
    async16(kg + (size_t)(b * TT + kbase + sr0 + 8) * 3072 + scol, kls + dof + 1024);
    async16(vg + kbase + scol, vls + dof);
    async16(vg + (size_t)8 * TT + kbase + scol, vls + dof + 1024);
  }

  f32x16 o[2][2] = {};
  f32x16 lb[2] = {};
  short8_t ones;
  #pragma unroll
  for (int i = 0; i < 8; ++i) ones[i] = (short)0x3C00;   // f16 1.0

  for (int it = 0; it < 16; ++it) {
    __syncthreads();                  // buf[it&1] staged; prior compute done
    if (it < 15) {
      const int kbase = ks * 1024 + (it + 1) * 64;
      const int bo = ((it + 1) & 1) * 8192;
      async16(kg + (size_t)(b * TT + kbase + sr0) * 3072 + scol, kls + bo + dof);
      async16(kg + (size_t)(b * TT + kbase + sr0 + 8) * 3072 + scol, kls + bo + dof + 1024);
      async16(vg + kbase + scol, vls + bo + dof);
      async16(vg + (size_t)8 * TT + kbase + scol, vls + bo + dof + 1024);
    }
    const char* Kb = kls + (it & 1) * 8192;
    const char* Vb = vls + (it & 1) * 8192;

    #pragma unroll
    for (int kt = 0; kt < 2; ++kt) {
      // ---- S^T = K Q^T (2 q-tiles share each K fragment) ----
      f32x16 s[2] = {};
      #pragma unroll
      for (int c = 0; c < 4; ++c) {
        const int krow = kt * 32 + l31;
        const short8_t kfr = *(const short8_t*)(Kb + krow * 128 + ((c * 32 + hl * 16) ^ swz));
        s[0] = mfma32(kfr, qf[0][c], s[0]);
        s[1] = mfma32(kfr, qf[1][c], s[1]);
      }
      // ---- P = 2^S in-register ----
      #pragma unroll
      for (int qt = 0; qt < 2; ++qt)
        #pragma unroll
        for (int r = 0; r < 16; ++r) {
          float pv;
          asm("v_exp_f32 %0, %1" : "=v"(pv) : "v"(s[qt][r]));
          s[qt][r] = pv;
        }
      // ---- pack to PV A-frags, l-MFMA, PV (V frags single b128, permuted keys) ----
      #pragma unroll
      for (int cc = 0; cc < 2; ++cc) {
        short8_t pa[2];
        #pragma unroll
        for (int qt = 0; qt < 2; ++qt) {
          int w0 = __builtin_bit_cast(int, __builtin_amdgcn_cvt_pkrtz(s[qt][8 * cc + 0], s[qt][8 * cc + 1]));
          int w1 = __builtin_bit_cast(int, __builtin_amdgcn_cvt_pkrtz(s[qt][8 * cc + 2], s[qt][8 * cc + 3]));
          int w2 = __builtin_bit_cast(int, __builtin_amdgcn_cvt_pkrtz(s[qt][8 * cc + 4], s[qt][8 * cc + 5]));
          int w3 = __builtin_bit_cast(int, __builtin_amdgcn_cvt_pkrtz(s[qt][8 * cc + 6], s[qt][8 * cc + 7]));
          int4v fw = {w0, w1, w2, w3};
          pa[qt] = __builtin_bit_cast(short8_t, fw);
          lb[qt] = mfma32(pa[qt], ones, lb[qt]);
        }
        const int cb = kt * 64 + cc * 32 + hl * 16;   // byte offset of pos-group
        #pragma unroll
        for (int dkt = 0; dkt < 2; ++dkt) {
          const int vrow = dkt * 32 + l31;
          const short8_t vfr = *(const short8_t*)(Vb + vrow * 128 + (cb ^ swz));
          o[0][dkt] = mfma32(pa[0], vfr, o[0][dkt]);
          o[1][dkt] = mfma32(pa[1], vfr, o[1][dkt]);
        }
      }
    }
  }

  // ---- cross-stream reduction through (now dead) staging LDS ----
  __syncthreads();                    // all LDS reads of the main loop done
  const int slot = qw * 64 + lane;    // 256 slots
  if (ks == 1) {
    u16* ro = (u16*)(smem + slot * 136);            // 64 f16, stride-padded
    #pragma unroll
    for (int qt = 0; qt < 2; ++qt)
      #pragma unroll
      for (int dkt = 0; dkt < 2; ++dkt)
        #pragma unroll
        for (int r = 0; r < 16; ++r)
          ro[(qt * 2 + dkt) * 16 + r] = f2h(o[qt][dkt][r]);
    u16* rl = (u16*)(smem + 36864 + slot * 72);     // 32 f16
    #pragma unroll
    for (int qt = 0; qt < 2; ++qt)
      #pragma unroll
      for (int r = 0; r < 16; ++r)
        rl[qt * 16 + r] = f2h(lb[qt][r]);
  }
  __syncthreads();
  if (ks == 0) {
    const u16* ro = (const u16*)(smem + slot * 136);
    const u16* rl = (const u16*)(smem + 36864 + slot * 72);
    #pragma unroll
    for (int qt = 0; qt < 2; ++qt) {
      #pragma unroll
      for (int r = 0; r < 16; ++r) lb[qt][r] += h2f(rl[qt * 16 + r]);
      #pragma unroll
      for (int dkt = 0; dkt < 2; ++dkt)
        #pragma unroll
        for (int r = 0; r < 16; ++r) o[qt][dkt][r] += h2f(ro[(qt * 2 + dkt) * 16 + r]);
    }
    #pragma unroll
    for (int qt = 0; qt < 2; ++qt) {
      float rlv[16];
      #pragma unroll
      for (int r = 0; r < 16; ++r) rlv[r] = 1.f / lb[qt][r];
      #pragma unroll
      for (int dkt = 0; dkt < 2; ++dkt) {
        const int col = h * 64 + dkt * 32 + l31;
        #pragma unroll
        for (int r = 0; r < 16; ++r) {
          const int rowg = b * TT + q0 + qt * 32 + (r & 3) + 8 * (r >> 2) + 4 * hl;
          zout[(size_t)rowg * 1024 + col] = f2h(o[qt][dkt][r] * rlv[r]);
        }
      }
    }
  }
}

// =======================================================================
// K6: final row softmax (logits f32 [4096][1024] -> out f32)
// =======================================================================
__global__ __launch_bounds__(256) void softmax_rows(const float* __restrict__ logits,
                                                    float* __restrict__ out) {
  __shared__ float sb[8];
  const int r = blockIdx.x, tid = threadIdx.x;
  float4 x = ((const float4*)(logits + (size_t)r * 1024))[tid];
  float mx = fmaxf(fmaxf(x.x, x.y), fmaxf(x.z, x.w));
  #pragma unroll
  for (int dd = 32; dd; dd >>= 1) mx = fmaxf(mx, __shfl_xor(mx, dd));
  if ((tid & 63) == 0) sb[tid >> 6] = mx;
  __syncthreads();
  mx = fmaxf(fmaxf(sb[0], sb[1]), fmaxf(sb[2], sb[3]));
  const float e0 = __expf(x.x - mx), e1 = __expf(x.y - mx);
  const float e2 = __expf(x.z - mx), e3 = __expf(x.w - mx);
  float s = e0 + e1 + e2 + e3;
  #pragma unroll
  for (int dd = 32; dd; dd >>= 1) s += __shfl_xor(s, dd);
  __syncthreads();
  if ((tid & 63) == 0) sb[4 + (tid >> 6)] = s;
  __syncthreads();
  s = sb[4] + sb[5] + sb[6] + sb[7];
  const float inv = 1.f / s;
  float4 o = {e0 * inv, e1 * inv, e2 * inv, e3 * inv};
  ((float4*)(out + (size_t)r * 1024))[tid] = o;
}

// =======================================================================
extern "C" void kernel_launch(void* const* d_in, const int* in_sizes, int n_in,
                              void* d_out, int out_size, void* d_ws, size_t ws_size,
                              hipStream_t stream) {
  (void)in_sizes; (void)n_in; (void)out_size; (void)ws_size;
  const float* p  = (const float*)d_in[0];
  const float* Wq = (const float*)d_in[1];
  const float* bq = (const float*)d_in[2];
  const float* Wk = (const float*)d_in[3];
  const float* bk = (const float*)d_in[4];
  const float* Wv = (const float*)d_in[5];
  const float* bv = (const float*)d_in[6];
  const float* Wo = (const float*)d_in[7];
  const float* bo = (const float*)d_in[8];
  float* out = (float*)d_out;

  char* ws = (char*)d_ws;
  u16*   wqkvt  = (u16*)(ws + O_WQKVT);
  u16*   wot    = (u16*)(ws + O_WOT);
  float* wmean  = (float*)(ws + O_WMEAN);
  float* bqkv_p = (float*)(ws + O_BQKV);
  float* bo_p   = (float*)(ws + O_BO);
  u16*   z      = (u16*)(ws + O_Z);
  u16*   qkv    = (u16*)(ws + O_QKV);
  u16*   vt     = (u16*)(ws + O_VT);
  u16*   zoutb  = (u16*)(ws + O_ZOUT);
  float* logits = (float*)(ws + O_LOGITS);

  wprep_mean<<<4100, 256, 0, stream>>>(Wq, Wk, Wv, Wo, bq, bk, bv, bo, wmean, bqkv_p, bo_p);
  wprep_trans<<<dim3(16, 16, 4), 256, 0, stream>>>(Wq, Wk, Wv, Wo, wmean, wqkvt, wot);
  clr_kernel<<<MR, 256, 0, stream>>>(p, z);
  gemm_qkv_8ph<<<512, 256, 0, stream>>>(z, wqkvt, bqkv_p, qkv, vt);
  attn_kernel<<<256, 512, 0, stream>>>(qkv, vt, zoutb);
  gemm_bt<<<dim3(1024 / 128, MR / 128), 256, 0, stream>>>(zoutb, wot, bo_p, logits, 1024, 1024);
  softmax_rows<<<MR, 256, 0, stream>>>(logits, out);
}

// Round 14
// 118.820 us; speedup vs baseline: 1.1399x; 1.0799x over previous
//
#include <hip/hip_runtime.h>

typedef unsigned short u16;
typedef __attribute__((ext_vector_type(8))) short short8_t;     // 8 x f16 payload (4 VGPR)
typedef __attribute__((ext_vector_type(8))) _Float16 half8_t;   // MFMA f16 operand
typedef __attribute__((ext_vector_type(4))) float f32x4;        // 16x16 MFMA accum
typedef __attribute__((ext_vector_type(16))) float f32x16;      // 32x32 MFMA accum
typedef __attribute__((ext_vector_type(4))) int int4v;

// ---- problem dims ----
#define BB    2
#define TT    2048
#define DD    1024
#define NHEAD 16
#define DKH   64
#define HH    1024
#define MR    4096          // B*T
#define CLR_EPS 1e-6f
// log2(e)/8 folded into Q so P = 2^(q'.k) = exp(q.k/8)
#define QSCALE_CONST 0.18033688011112042f

// ---- workspace byte offsets ----
#define O_WQKVT  0ull                 // f16 [3072][1024]
#define O_WOT    6291456ull           // f16 [1024][1024]
#define O_WMEAN  8388608ull           // f32  [4][1024]
#define O_BQKV   8404992ull           // f32  [3072]
#define O_BO     8417280ull           // f32  [1024]
#define O_Z      8421376ull           // f16 [4096][1024]
#define O_QKV    16809984ull          // f16 [4096][3072]  (q|k cols; v third unused)
#define O_VT     41975808ull          // f16 [B*NH][64][2048]  (keys PERMUTED within 32-groups)
#define O_ZOUT   50364416ull          // f16 [4096][1024]
#define O_LOGITS O_QKV                // f32  [4096][1024] (reuses dead qkv region)

// ---------------- helpers ----------------
__device__ __forceinline__ u16 f2h(float f) {
  _Float16 h = (_Float16)f;           // v_cvt_f16_f32 (RNE)
  return __builtin_bit_cast(u16, h);
}
__device__ __forceinline__ float h2f(u16 x) {
  return (float)__builtin_bit_cast(_Float16, x);
}

__device__ __forceinline__ f32x4 mfma16(short8_t a, short8_t b, f32x4 c) {
  return __builtin_amdgcn_mfma_f32_16x16x32_f16(
      __builtin_bit_cast(half8_t, a), __builtin_bit_cast(half8_t, b), c, 0, 0, 0);
}
__device__ __forceinline__ f32x16 mfma32(short8_t a, short8_t b, f32x16 c) {
  return __builtin_amdgcn_mfma_f32_32x32x16_f16(
      __builtin_bit_cast(half8_t, a), __builtin_bit_cast(half8_t, b), c, 0, 0, 0);
}

typedef const __attribute__((address_space(1))) unsigned int as1_u32_t;
typedef __attribute__((address_space(3))) unsigned int as3_u32_t;

__device__ __forceinline__ void async16(const void* g, void* l) {
  __builtin_amdgcn_global_load_lds((as1_u32_t*)g, (as3_u32_t*)l, 16, 0, 0);
}

// swizzled ds_read of one 16x16x32 A/B fragment from a [*][64] f16 tile
__device__ __forceinline__ short8_t ldfrag(const u16* buf, int row, int kh, int lane) {
  const int byte = (row * 128 + ((kh * 32 + ((lane >> 4) << 3)) << 1)) ^ ((row & 7) << 4);
  return *(const short8_t*)((const char*)buf + byte);
}

// =======================================================================
// K0a: weight row-means (mean over out-dim h for each in-dim d) + biases
// =======================================================================
__global__ __launch_bounds__(256) void wprep_mean(
    const float* __restrict__ Wq, const float* __restrict__ Wk,
    const float* __restrict__ Wv, const float* __restrict__ Wo,
    const float* __restrict__ bq, const float* __restrict__ bk,
    const float* __restrict__ bv, const float* __restrict__ bo,
    float* __restrict__ wmean, float* __restrict__ bqkv_p, float* __restrict__ bo_p) {
  __shared__ float sb[4];
  const int bid = blockIdx.x, tid = threadIdx.x;
  if (bid < 4096) {
    const int m = bid >> 10, d = bid & 1023;
    const float* Wm = (m == 0) ? Wq : (m == 1) ? Wk : (m == 2) ? Wv : Wo;
    float4 x = ((const float4*)(Wm + (size_t)d * 1024))[tid];
    float s = x.x + x.y + x.z + x.w;
    #pragma unroll
    for (int dd = 32; dd; dd >>= 1) s += __shfl_xor(s, dd);
    if ((tid & 63) == 0) sb[tid >> 6] = s;
    __syncthreads();
    if (tid == 0) wmean[bid] = (sb[0] + sb[1] + sb[2] + sb[3]) * (1.f / 1024.f);
  } else {
    const int j = bid - 4096;
    const float* bb = (j == 0) ? bq : (j == 1) ? bk : (j == 2) ? bv : bo;
    float4 x = ((const float4*)bb)[tid];
    float s = x.x + x.y + x.z + x.w;
    #pragma unroll
    for (int dd = 32; dd; dd >>= 1) s += __shfl_xor(s, dd);
    if ((tid & 63) == 0) sb[tid >> 6] = s;
    __syncthreads();
    const float mean = (sb[0] + sb[1] + sb[2] + sb[3]) * (1.f / 1024.f);
    float* dst = (j < 3) ? (bqkv_p + j * 1024) : bo_p;
    float4 o = {x.x - mean, x.y - mean, x.z - mean, x.w - mean};
    ((float4*)dst)[tid] = o;
  }
}

// =======================================================================
// K0b: transpose weights, subtract row-mean, cast f16.
// =======================================================================
__global__ __launch_bounds__(256) void wprep_trans(
    const float* __restrict__ Wq, const float* __restrict__ Wk,
    const float* __restrict__ Wv, const float* __restrict__ Wo,
    const float* __restrict__ wmean, u16* __restrict__ wqkvt, u16* __restrict__ wot) {
  __shared__ float tl[64][65];
  const int tj = blockIdx.x, ti = blockIdx.y, m = blockIdx.z;
  const int tid = threadIdx.x;
  const float* Wm = (m == 0) ? Wq : (m == 1) ? Wk : (m == 2) ? Wv : Wo;
  const int d0 = ti * 64, h0 = tj * 64;
  #pragma unroll
  for (int rr = 0; rr < 4; ++rr) {
    const int r = (tid >> 4) + rr * 16;
    float4 x = *(const float4*)(Wm + (size_t)(d0 + r) * 1024 + h0 + ((tid & 15) << 2));
    const float mu = wmean[m * 1024 + d0 + r];
    tl[r][(tid & 15) * 4 + 0] = x.x - mu;
    tl[r][(tid & 15) * 4 + 1] = x.y - mu;
    tl[r][(tid & 15) * 4 + 2] = x.z - mu;
    tl[r][(tid & 15) * 4 + 3] = x.w - mu;
  }
  __syncthreads();
  #pragma unroll
  for (int rr = 0; rr < 2; ++rr) {
    const int hh = (tid >> 3) + rr * 32;
    const int cd = (tid & 7) << 3;
    short8_t v;
    #pragma unroll
    for (int i = 0; i < 8; ++i) v[i] = (short)f2h(tl[cd + i][hh]);
    u16* dst = (m < 3) ? (wqkvt + ((size_t)(m * 1024 + h0 + hh)) * 1024 + d0 + cd)
                       : (wot + ((size_t)(h0 + hh)) * 1024 + d0 + cd);
    *(short8_t*)dst = v;
  }
}

// =======================================================================
// K1: CLR: z = log(p+eps) - rowmean, f16   (one block per row)
// =======================================================================
__global__ __launch_bounds__(256) void clr_kernel(const float* __restrict__ p, u16* __restrict__ z) {
  __shared__ float sb[4];
  const int r = blockIdx.x, tid = threadIdx.x;
  float4 x = ((const float4*)(p + (size_t)r * 1024))[tid];
  float l0 = __logf(x.x + CLR_EPS), l1 = __logf(x.y + CLR_EPS);
  float l2 = __logf(x.z + CLR_EPS), l3 = __logf(x.w + CLR_EPS);
  float s = l0 + l1 + l2 + l3;
  #pragma unroll
  for (int dd = 32; dd; dd >>= 1) s += __shfl_xor(s, dd);
  if ((tid & 63) == 0) sb[tid >> 6] = s;
  __syncthreads();
  const float mu = (sb[0] + sb[1] + sb[2] + sb[3]) * (1.f / 1024.f);
  ushort4 o;
  o.x = f2h(l0 - mu); o.y = f2h(l1 - mu); o.z = f2h(l2 - mu); o.w = f2h(l3 - mu);
  ((ushort4*)(z + (size_t)r * 1024))[tid] = o;
}

// =======================================================================
// K2 v3: QKV GEMM, f16, 128x192 tile, BK=64, 4 waves, 80KB LDS,
//  grid 512 = 2 blocks/CU, XCD-grouped. (R13 verbatim — passing.)
// =======================================================================
__global__ __launch_bounds__(256, 2) void gemm_qkv_8ph(
    const u16* __restrict__ A, const u16* __restrict__ Bt, const float* __restrict__ bias,
    u16* __restrict__ qkv, u16* __restrict__ vt) {
  __shared__ u16 As[2][128 * 64];   // 32 KB
  __shared__ u16 Bs[2][192 * 64];   // 48 KB
  const int tid = threadIdx.x, lane = tid & 63, w = tid >> 6;
  const int wm = w >> 1, wn = w & 1;          // wave tile 64x96
  const int id = blockIdx.x;
  const int x = id & 7, idx = id >> 3;        // idx 0..63
  const int mt = (x & 3) * 8 + (idx & 7);     // 0..31
  const int nt = (x >> 2) * 8 + (idx >> 3);   // 0..15
  const int m0 = mt * 128, n0 = nt * 192;
  const int srow = tid >> 3, schk = tid & 7;  // staging: 32 rows/round
  const int l15 = lane & 15, lg4 = (lane >> 4) << 2;

  f32x4 acc[4][6] = {};

  auto stA = [&](int k0, int buf) {
    #pragma unroll
    for (int u = 0; u < 4; ++u) {
      const int r = srow + u * 32;
      const int c = k0 + ((schk ^ (r & 7)) << 3);
      async16(A + (size_t)(m0 + r) * 1024 + c, &As[buf][r * 64 + schk * 8]);
    }
  };
  auto stB = [&](int k0, int buf) {
    #pragma unroll
    for (int u = 0; u < 6; ++u) {
      const int r = srow + u * 32;
      const int c = k0 + ((schk ^ (r & 7)) << 3);
      async16(Bt + (size_t)(n0 + r) * 1024 + c, &Bs[buf][r * 64 + schk * 8]);
    }
  };

  // prologue: tile 0
  stA(0, 0); stB(0, 0);
  asm volatile("s_waitcnt vmcnt(0)" ::: "memory");
  __builtin_amdgcn_s_barrier();

  short8_t afr[4], bfr[6];
  for (int t = 0; t < 16; ++t) {
    const int cur = t & 1;
    const int k0n = ((t + 1) & 15) * 64;      // wraps to 0 on last iter (dummy)
    const u16* Ab = &As[cur][0];
    const u16* Bb_ = &Bs[cur][0];

    // ---------- P1 (kh0): read frags, stage tile t+1 ----------
    #pragma unroll
    for (int j = 0; j < 6; ++j) bfr[j] = ldfrag(Bb_, wn * 96 + j * 16 + l15, 0, lane);
    #pragma unroll
    for (int i = 0; i < 4; ++i) afr[i] = ldfrag(Ab, wm * 64 + i * 16 + l15, 0, lane);
    stA(k0n, cur ^ 1); stB(k0n, cur ^ 1);
    __builtin_amdgcn_s_barrier();
    asm volatile("s_waitcnt lgkmcnt(0)" ::: "memory");
    __builtin_amdgcn_sched_barrier(0);
    __builtin_amdgcn_s_setprio(1);
    #pragma unroll
    for (int i = 0; i < 4; ++i)
      #pragma unroll
      for (int j = 0; j < 6; ++j)
        acc[i][j] = mfma16(afr[i], bfr[j], acc[i][j]);
    __builtin_amdgcn_s_setprio(0);
    __builtin_amdgcn_s_barrier();

    // ---------- P2 (kh1): read frags; gate tile t+1 after MFMA ----------
    #pragma unroll
    for (int j = 0; j < 6; ++j) bfr[j] = ldfrag(Bb_, wn * 96 + j * 16 + l15, 1, lane);
    #pragma unroll
    for (int i = 0; i < 4; ++i) afr[i] = ldfrag(Ab, wm * 64 + i * 16 + l15, 1, lane);
    __builtin_amdgcn_s_barrier();
    asm volatile("s_waitcnt lgkmcnt(0)" ::: "memory");
    __builtin_amdgcn_sched_barrier(0);
    __builtin_amdgcn_s_setprio(1);
    #pragma unroll
    for (int i = 0; i < 4; ++i)
      #pragma unroll
      for (int j = 0; j < 6; ++j)
        acc[i][j] = mfma16(afr[i], bfr[j], acc[i][j]);
    __builtin_amdgcn_s_setprio(0);
    asm volatile("s_waitcnt vmcnt(0)" ::: "memory");  // tile t+1 landed (1.5 phases slack)
    __builtin_amdgcn_s_barrier();                     // gates next-iter reads + overwrite
  }

  // ---- epilogue: per-frag column branch ----
  #pragma unroll
  for (int j = 0; j < 6; ++j) {
    const int col = n0 + wn * 96 + j * 16 + l15;
    const float bb = bias[col];
    if (col < 2048) {
      const float sc = (col < 1024) ? QSCALE_CONST : 1.0f;
      #pragma unroll
      for (int i = 0; i < 4; ++i) {
        const int rowb = m0 + wm * 64 + i * 16 + lg4;
        #pragma unroll
        for (int r = 0; r < 4; ++r)
          qkv[(size_t)(rowb + r) * 3072 + col] = f2h((acc[i][j][r] + bb) * sc);
      }
    } else {
      // V: transposed + key-permuted into vt[(b*16+h)*64+dk][pos(t)]
      const int h = (col - 2048) >> 6, dk = col & 63;
      #pragma unroll
      for (int i = 0; i < 4; ++i) {
        const int rowb = m0 + wm * 64 + i * 16 + lg4;   // mult of 4
        const int b = rowb >> 11, tq = rowb & 2047;
        const int k5 = tq & 31;
        const int pos = (tq & ~31) + (k5 & 16) + ((k5 & 4) << 1) + ((k5 & 8) >> 1);
        ushort4 pk;
        pk.x = f2h(acc[i][j][0] + bb);
        pk.y = f2h(acc[i][j][1] + bb);
        pk.z = f2h(acc[i][j][2] + bb);
        pk.w = f2h(acc[i][j][3] + bb);
        *(ushort4*)(vt + ((size_t)((b * NHEAD + h) * 64 + dk)) * TT + pos) = pk;
      }
    }
  }
}

// =======================================================================
// K5 v2: f16 GEMM (out-proj, f32 out), 128x64 tiles -> grid 16x32 = 512
//  blocks, LDS 48KB -> 3 blocks/CU (independent blocks hide each other's
//  barrier/LDS phases). Full-K ascending accumulation, same MFMA shape
//  and kk order as R13 -> bit-exact. bx-fast grid: same-bx blocks all
//  land on XCD bx%8 (B panel L2-local).
// =======================================================================
__global__ __launch_bounds__(256, 3) void gemm_bt(
    const u16* __restrict__ A, const u16* __restrict__ Bt, const float* __restrict__ bias,
    float* __restrict__ Cout, int Ndim, int Kdim) {
  __shared__ u16 As[2][128 * 64];   // 32 KB
  __shared__ u16 Bs[2][64 * 64];    // 16 KB
  const int tid = threadIdx.x;
  const int lane = tid & 63, wid = tid >> 6;
  const int m0 = blockIdx.y * 128, n0 = blockIdx.x * 64;
  const int wm = wid >> 1, wn = wid & 1;      // wave tile 64x32
  const int srow = tid >> 3, schk = tid & 7;
  f32x4 acc[4][2] = {};

  auto STG = [&](int k0, int buf) {
    #pragma unroll
    for (int rr = 0; rr < 4; ++rr) {
      const int row = srow + rr * 32;
      const int gcol = k0 + ((schk ^ (row & 7)) << 3);
      async16(A + (size_t)(m0 + row) * Kdim + gcol, &As[buf][row * 64 + schk * 8]);
      if (rr < 2)
        async16(Bt + (size_t)(n0 + row) * Kdim + gcol, &Bs[buf][row * 64 + schk * 8]);
    }
  };

  STG(0, 0);
  asm volatile("s_waitcnt vmcnt(0)" ::: "memory");
  __builtin_amdgcn_s_barrier();

  const int ntk = Kdim >> 6;          // 16 for K=1024
  for (int t = 0; t < ntk; ++t) {
    const int cur = t & 1;
    STG((((t + 1) & (ntk - 1))) << 6, cur ^ 1);   // wraps -> dummy on last iter
    #pragma unroll
    for (int kk = 0; kk < 2; ++kk) {
      short8_t af[4], bf[2];
      #pragma unroll
      for (int i = 0; i < 4; ++i)
        af[i] = ldfrag(&As[cur][0], wm * 64 + i * 16 + (lane & 15), kk, lane);
      #pragma unroll
      for (int j = 0; j < 2; ++j)
        bf[j] = ldfrag(&Bs[cur][0], wn * 32 + j * 16 + (lane & 15), kk, lane);
      __builtin_amdgcn_s_setprio(1);
      #pragma unroll
      for (int i = 0; i < 4; ++i)
        #pragma unroll
        for (int j = 0; j < 2; ++j)
          acc[i][j] = mfma16(af[i], bf[j], acc[i][j]);
      __builtin_amdgcn_s_setprio(0);
    }
    asm volatile("s_waitcnt vmcnt(0)" ::: "memory");  // tile t+1 landed
    __builtin_amdgcn_s_barrier();                     // all reads of buf cur done
  }

  #pragma unroll
  for (int j = 0; j < 2; ++j) {
    const int col = n0 + wn * 32 + j * 16 + (lane & 15);
    const float bb = bias[col];
    #pragma unroll
    for (int i = 0; i < 4; ++i) {
      const int rowb = m0 + wm * 64 + i * 16 + ((lane >> 4) << 2);
      #pragma unroll
      for (int r = 0; r < 4; ++r)
        Cout[(size_t)(rowb + r) * Ndim + col] = acc[i][j][r] + bb;
    }
  }
}

// =======================================================================
// K4: flash attention — R11 data/accumulation order VERBATIM, with a
//  bit-exact ILP restructure: both kt QK-MFMA groups issue first into
//  s[2][2], then all exps, then pack+l+PV in the ORIGINAL per-accumulator
//  order (lb/o receive identical MFMA sequences -> bit-identical output).
//  setprio(1) brackets the MFMA clusters (T5: runtime arbitration only).
//  Structure otherwise frozen (5/5 pass record).
// =======================================================================
__global__ __launch_bounds__(512, 2) void attn_kernel(
    const u16* __restrict__ qkv, const u16* __restrict__ vt, u16* __restrict__ zout) {
  __shared__ char smem[65536];   // [0,32K): K[stream][buf]; [32K,64K): V[stream][buf]
  const int id = blockIdx.x;
  const int qb = (id >> 3) & 7;
  const int bh = (id & 7) * 4 + (id >> 6);    // id%8 = XCD owns 4 (b,h) pairs
  const int b = bh >> 4, h = bh & 15;
  const int tid = threadIdx.x, lane = tid & 63, w = tid >> 6;
  const int qw = w & 3, ks = w >> 2;
  const int hl = lane >> 5, l31 = lane & 31;
  const int swz = (l31 & 7) << 4;
  const int q0 = qb * 256 + qw * 64;

  // ---- Q B-frags from global: qf[qt][c] elem j = Q[q0+qt*32+l31][c*16+hl*8+j] ----
  short8_t qf[2][4];
  #pragma unroll
  for (int qt = 0; qt < 2; ++qt)
    #pragma unroll
    for (int c = 0; c < 4; ++c)
      qf[qt][c] = *(const short8_t*)(qkv + (size_t)(b * TT + q0 + qt * 32 + l31) * 3072
                                     + h * 64 + c * 16 + hl * 8);

  // ---- staging geometry: stream's 4 waves cover rows 0..63 (wave qw: 16 rows) ----
  const int sr0 = qw * 16 + (lane >> 3);      // and sr0+8
  const int schk = lane & 7;
  const int scol = (schk ^ (sr0 & 7)) << 3;   // inverse-swizzled source col (elems)
  const int dof = sr0 * 128 + schk * 16;      // LDS byte offset within a tile
  char* kls = smem + ks * 16384;              // this stream's K bufs (+0 / +8192)
  char* vls = smem + 32768 + ks * 16384;
  const u16* kg = qkv + 1024 + (size_t)h * 64;
  const u16* vg = vt + ((size_t)(b * NHEAD + h) * 64 + sr0) * (size_t)TT;

  // prologue: stage tile 0
  {
    const int kbase = ks * 1024;
    async16(kg + (size_t)(b * TT + kbase + sr0) * 3072 + scol, kls + dof);
    async16(kg + (size_t)(b * TT + kbase + sr0 + 8) * 3072 + scol, kls + dof + 1024);
    async16(vg + kbase + scol, vls + dof);
    async16(vg + (size_t)8 * TT + kbase + scol, vls + dof + 1024);
  }

  f32x16 o[2][2] = {};
  f32x16 lb[2] = {};
  short8_t ones;
  #pragma unroll
  for (int i = 0; i < 8; ++i) ones[i] = (short)0x3C00;   // f16 1.0

  for (int it = 0; it < 16; ++it) {
    __syncthreads();                  // buf[it&1] staged; prior compute done
    if (it < 15) {
      const int kbase = ks * 1024 + (it + 1) * 64;
      const int bo = ((it + 1) & 1) * 8192;
      async16(kg + (size_t)(b * TT + kbase + sr0) * 3072 + scol, kls + bo + dof);
      async16(kg + (size_t)(b * TT + kbase + sr0 + 8) * 3072 + scol, kls + bo + dof + 1024);
      async16(vg + kbase + scol, vls + bo + dof);
      async16(vg + (size_t)8 * TT + kbase + scol, vls + bo + dof + 1024);
    }
    const char* Kb = kls + (it & 1) * 8192;
    const char* Vb = vls + (it & 1) * 8192;

    // ---- phase 1: ALL QK^T MFMAs (both kt) into s[kt][qt] ----
    f32x16 s[2][2] = {};
    __builtin_amdgcn_s_setprio(1);
    #pragma unroll
    for (int kt = 0; kt < 2; ++kt) {
      #pragma unroll
      for (int c = 0; c < 4; ++c) {
        const int krow = kt * 32 + l31;
        const short8_t kfr = *(const short8_t*)(Kb + krow * 128 + ((c * 32 + hl * 16) ^ swz));
        s[kt][0] = mfma32(kfr, qf[0][c], s[kt][0]);
        s[kt][1] = mfma32(kfr, qf[1][c], s[kt][1]);
      }
    }
    __builtin_amdgcn_s_setprio(0);

    // ---- phase 2: ALL exps (elementwise; order irrelevant) ----
    #pragma unroll
    for (int kt = 0; kt < 2; ++kt)
      #pragma unroll
      for (int qt = 0; qt < 2; ++qt)
        #pragma unroll
        for (int r = 0; r < 16; ++r) {
          float pv;
          asm("v_exp_f32 %0, %1" : "=v"(pv) : "v"(s[kt][qt][r]));
          s[kt][qt][r] = pv;
        }

    // ---- phase 3: pack + l-MFMA + PV in ORIGINAL accumulation order ----
    #pragma unroll
    for (int kt = 0; kt < 2; ++kt) {
      #pragma unroll
      for (int cc = 0; cc < 2; ++cc) {
        short8_t pa[2];
        #pragma unroll
        for (int qt = 0; qt < 2; ++qt) {
          int w0 = __builtin_bit_cast(int, __builtin_amdgcn_cvt_pkrtz(s[kt][qt][8 * cc + 0], s[kt][qt][8 * cc + 1]));
          int w1 = __builtin_bit_cast(int, __builtin_amdgcn_cvt_pkrtz(s[kt][qt][8 * cc + 2], s[kt][qt][8 * cc + 3]));
          int w2 = __builtin_bit_cast(int, __builtin_amdgcn_cvt_pkrtz(s[kt][qt][8 * cc + 4], s[kt][qt][8 * cc + 5]));
          int w3 = __builtin_bit_cast(int, __builtin_amdgcn_cvt_pkrtz(s[kt][qt][8 * cc + 6], s[kt][qt][8 * cc + 7]));
          int4v fw = {w0, w1, w2, w3};
          pa[qt] = __builtin_bit_cast(short8_t, fw);
          lb[qt] = mfma32(pa[qt], ones, lb[qt]);
        }
        const int cb = kt * 64 + cc * 32 + hl * 16;   // byte offset of pos-group
        __builtin_amdgcn_s_setprio(1);
        #pragma unroll
        for (int dkt = 0; dkt < 2; ++dkt) {
          const int vrow = dkt * 32 + l31;
          const short8_t vfr = *(const short8_t*)(Vb + vrow * 128 + (cb ^ swz));
          o[0][dkt] = mfma32(pa[0], vfr, o[0][dkt]);
          o[1][dkt] = mfma32(pa[1], vfr, o[1][dkt]);
        }
        __builtin_amdgcn_s_setprio(0);
      }
    }
  }

  // ---- cross-stream reduction through (now dead) staging LDS ----
  __syncthreads();                    // all LDS reads of the main loop done
  const int slot = qw * 64 + lane;    // 256 slots
  if (ks == 1) {
    u16* ro = (u16*)(smem + slot * 136);            // 64 f16, stride-padded
    #pragma unroll
    for (int qt = 0; qt < 2; ++qt)
      #pragma unroll
      for (int dkt = 0; dkt < 2; ++dkt)
        #pragma unroll
        for (int r = 0; r < 16; ++r)
          ro[(qt * 2 + dkt) * 16 + r] = f2h(o[qt][dkt][r]);
    u16* rl = (u16*)(smem + 36864 + slot * 72);     // 32 f16
    #pragma unroll
    for (int qt = 0; qt < 2; ++qt)
      #pragma unroll
      for (int r = 0; r < 16; ++r)
        rl[qt * 16 + r] = f2h(lb[qt][r]);
  }
  __syncthreads();
  if (ks == 0) {
    const u16* ro = (const u16*)(smem + slot * 136);
    const u16* rl = (const u16*)(smem + 36864 + slot * 72);
    #pragma unroll
    for (int qt = 0; qt < 2; ++qt) {
      #pragma unroll
      for (int r = 0; r < 16; ++r) lb[qt][r] += h2f(rl[qt * 16 + r]);
      #pragma unroll
      for (int dkt = 0; dkt < 2; ++dkt)
        #pragma unroll
        for (int r = 0; r < 16; ++r) o[qt][dkt][r] += h2f(ro[(qt * 2 + dkt) * 16 + r]);
    }
    #pragma unroll
    for (int qt = 0; qt < 2; ++qt) {
      float rlv[16];
      #pragma unroll
      for (int r = 0; r < 16; ++r) rlv[r] = 1.f / lb[qt][r];
      #pragma unroll
      for (int dkt = 0; dkt < 2; ++dkt) {
        const int col = h * 64 + dkt * 32 + l31;
        #pragma unroll
        for (int r = 0; r < 16; ++r) {
          const int rowg = b * TT + q0 + qt * 32 + (r & 3) + 8 * (r >> 2) + 4 * hl;
          zout[(size_t)rowg * 1024 + col] = f2h(o[qt][dkt][r] * rlv[r]);
        }
      }
    }
  }
}

// =======================================================================
// K6: final row softmax (logits f32 [4096][1024] -> out f32)
// =======================================================================
__global__ __launch_bounds__(256) void softmax_rows(const float* __restrict__ logits,
                                                    float* __restrict__ out) {
  __shared__ float sb[8];
  const int r = blockIdx.x, tid = threadIdx.x;
  float4 x = ((const float4*)(logits + (size_t)r * 1024))[tid];
  float mx = fmaxf(fmaxf(x.x, x.y), fmaxf(x.z, x.w));
  #pragma unroll
  for (int dd = 32; dd; dd >>= 1) mx = fmaxf(mx, __shfl_xor(mx, dd));
  if ((tid & 63) == 0) sb[tid >> 6] = mx;
  __syncthreads();
  mx = fmaxf(fmaxf(sb[0], sb[1]), fmaxf(sb[2], sb[3]));
  const float e0 = __expf(x.x - mx), e1 = __expf(x.y - mx);
  const float e2 = __expf(x.z - mx), e3 = __expf(x.w - mx);
  float s = e0 + e1 + e2 + e3;
  #pragma unroll
  for (int dd = 32; dd; dd >>= 1) s += __shfl_xor(s, dd);
  __syncthreads();
  if ((tid & 63) == 0) sb[4 + (tid >> 6)] = s;
  __syncthreads();
  s = sb[4] + sb[5] + sb[6] + sb[7];
  const float inv = 1.f / s;
  float4 o = {e0 * inv, e1 * inv, e2 * inv, e3 * inv};
  ((float4*)(out + (size_t)r * 1024))[tid] = o;
}

// =======================================================================
extern "C" void kernel_launch(void* const* d_in, const int* in_sizes, int n_in,
                              void* d_out, int out_size, void* d_ws, size_t ws_size,
                              hipStream_t stream) {
  (void)in_sizes; (void)n_in; (void)out_size; (void)ws_size;
  const float* p  = (const float*)d_in[0];
  const float* Wq = (const float*)d_in[1];
  const float* bq = (const float*)d_in[2];
  const float* Wk = (const float*)d_in[3];
  const float* bk = (const float*)d_in[4];
  const float* Wv = (const float*)d_in[5];
  const float* bv = (const float*)d_in[6];
  const float* Wo = (const float*)d_in[7];
  const float* bo = (const float*)d_in[8];
  float* out = (float*)d_out;

  char* ws = (char*)d_ws;
  u16*   wqkvt  = (u16*)(ws + O_WQKVT);
  u16*   wot    = (u16*)(ws + O_WOT);
  float* wmean  = (float*)(ws + O_WMEAN);
  float* bqkv_p = (float*)(ws + O_BQKV);
  float* bo_p   = (float*)(ws + O_BO);
  u16*   z      = (u16*)(ws + O_Z);
  u16*   qkv    = (u16*)(ws + O_QKV);
  u16*   vt     = (u16*)(ws + O_VT);
  u16*   zoutb  = (u16*)(ws + O_ZOUT);
  float* logits = (float*)(ws + O_LOGITS);

  wprep_mean<<<4100, 256, 0, stream>>>(Wq, Wk, Wv, Wo, bq, bk, bv, bo, wmean, bqkv_p, bo_p);
  wprep_trans<<<dim3(16, 16, 4), 256, 0, stream>>>(Wq, Wk, Wv, Wo, wmean, wqkvt, wot);
  clr_kernel<<<MR, 256, 0, stream>>>(p, z);
  gemm_qkv_8ph<<<512, 256, 0, stream>>>(z, wqkvt, bqkv_p, qkv, vt);
  attn_kernel<<<256, 512, 0, stream>>>(qkv, vt, zoutb);
  gemm_bt<<<dim3(1024 / 64, MR / 128), 256, 0, stream>>>(zoutb, wot, bo_p, logits, 1024, 1024);
  softmax_rows<<<MR, 256, 0, stream>>>(logits, out);
}